// Round 11
// baseline (65.896 us; speedup 1.0000x reference)
//
#include <hip/hip_runtime.h>
#include <hip/hip_bf16.h>
#include <math.h>

typedef short bf16x8 __attribute__((ext_vector_type(8)));
typedef float f32x4  __attribute__((ext_vector_type(4)));

static __device__ __forceinline__ unsigned short f2bf(float x) {
    unsigned u = __builtin_bit_cast(unsigned, x);
    return (unsigned short)((u + 0x7fffu + ((u >> 16) & 1u)) >> 16);
}

static __device__ __forceinline__ bf16x8 pack8(float4 u0, float4 u1) {
    bf16x8 f;
    f[0] = (short)f2bf(u0.x); f[1] = (short)f2bf(u0.y);
    f[2] = (short)f2bf(u0.z); f[3] = (short)f2bf(u0.w);
    f[4] = (short)f2bf(u1.x); f[5] = (short)f2bf(u1.y);
    f[6] = (short)f2bf(u1.z); f[7] = (short)f2bf(u1.w);
    return f;
}

static __device__ __forceinline__ void async_cp16(const void* gsrc, void* ldsdst) {
    __builtin_amdgcn_global_load_lds(
        (const __attribute__((address_space(1))) void*)gsrc,
        (__attribute__((address_space(3))) void*)ldsdst, 16, 0, 0);
}

// ---- cent_prep (wide): 256 thr; blocks [0,nblk): image+c2; block nblk: zero --
// img[cb16][k][lane][j] = cent[cb16*16 + (lane&15)][k*32 + (lane>>4)*8 + j]
__global__ __launch_bounds__(256) void cent_prep_kernel(
    const float* __restrict__ cent, char* __restrict__ Cimg,
    float* __restrict__ c2g, float* __restrict__ out, int out_size,
    int ncb, int nblk) {
    const int tid = threadIdx.x, lane = tid & 63, wv = tid >> 6;
    if ((int)blockIdx.x < nblk) {
        const int cb = blockIdx.x * 4 + wv;
        if (cb < ncb) {
            const int r = cb * 16 + (lane & 15);
            const int q = lane >> 4;
            const float4* C4 = (const float4*)cent;
            float s = 0.0f;
            #pragma unroll
            for (int k = 0; k < 8; ++k) {
                int fidx = r * 64 + k * 8 + q * 2;
                float4 u0 = C4[fidx], u1 = C4[fidx + 1];
                *(bf16x8*)(Cimg + ((size_t)(cb * 8 + k) * 64 + lane) * 16) = pack8(u0, u1);
                s += u0.x*u0.x + u0.y*u0.y + u0.z*u0.z + u0.w*u0.w
                   + u1.x*u1.x + u1.y*u1.y + u1.z*u1.z + u1.w*u1.w;
            }
            s += __shfl_xor(s, 16, 64);
            s += __shfl_xor(s, 32, 64);
            if (lane < 16) c2g[cb * 16 + lane] = s;
        }
    } else {
        for (int i = tid; i < out_size; i += 256) out[i] = 0.0f;
    }
}

// ---- main7: 512 blocks x 256 thr (4 waves); wave = 64 rows x 16 cols. -------
// A converted fp32->bf16 inline into a[4][8] (no workspace round-trip).
// e2+c2 folded into acc init => d2 = -2*acc. pos = label-column select of the
// MFMA dot (bf16 accuracy, validated R1/R6/R10; error sum/B ~1e-3 << tol).
// Labels: per-block self-detect of int32/int64 from a fixed 32KB window.
// B: 64-col chunks (32KB) double-buffered via global_load_lds; 4 MFMA/ds_read.
//
// __launch_bounds__(256, 1) is THE critical knob: empirically (R4/R5/R7/R10),
// 512-thread blocks and any >=2-waves/EU hint make hipcc cap VGPRs at 128 and
// spill the 128-VGPR a[4][8] array to scratch (43+ MB of WRITE_SIZE). Only
// (256,1) unlocks the 256-VGPR budget (R9's main6 evidence). At ~200 VGPR
// occupancy is still 8 waves/CU = 2 blocks/CU, matching the 69.7KB LDS limit.
#define CHUNK_BYTES 32768
// LDS: chunks @0 (2x32KB), c2l @65536 (4KB), det @69632 (16B), red @69648 (16B)
#define MAIN_SMEM 69664

__global__ __launch_bounds__(256, 1) void main7_kernel(
    const float* __restrict__ emb, const char* __restrict__ Cimg,
    const float* __restrict__ c2g, const int* __restrict__ labw, int lab_nelem,
    float* __restrict__ out, int K, int nchunk, float invB) {
    extern __shared__ char smem[];
    float*    c2l = (float*)(smem + 65536);
    unsigned* det = (unsigned*)(smem + 69632);
    float*    red = (float*)(smem + 69648);

    const int tid = threadIdx.x, lane = tid & 63, wid = tid >> 6; // wid = col16
    const int brow0 = blockIdx.x * 64;
    const int l15 = lane & 15, q = lane >> 4;

    // issue chunk-0 fills first (latency hidden under prologue)
    #pragma unroll
    for (int i = 0; i < 8; ++i)
        async_cp16(Cimg + (size_t)(i * 256 + tid) * 16, smem + (i * 256 + tid) * 16);

    // c2 -> LDS
    for (int i = tid; i < K; i += 256) c2l[i] = c2g[i];

    // label-width detect from a fixed window (identical result in all blocks)
    {
        int npairs = lab_nelem / 2; if (npairs > 4096) npairs = 4096;
        unsigned accw = 0;
        const unsigned* w = (const unsigned*)labw;
        for (int i = tid; i < npairs; i += 256) accw |= w[2 * i + 1];
        #pragma unroll
        for (int d = 32; d >= 1; d >>= 1) accw |= __shfl_xor(accw, d, 64);
        if (lane == 0) det[wid] = accw;
    }
    __syncthreads();
    const int is32 = ((det[0] | det[1] | det[2] | det[3]) != 0);
    const int lab_self = is32 ? labw[brow0 + lane] : labw[2 * (brow0 + lane)];

    // A: 64 rows -> bf16 fragments in regs; e2 per row via shfl
    bf16x8 a[4][8];
    float e2m[4];
    #pragma unroll
    for (int m = 0; m < 4; ++m) {
        const int rg = brow0 + m * 16 + l15;
        const float4* E4 = (const float4*)emb + (size_t)rg * 64;
        float s = 0.0f;
        #pragma unroll
        for (int k = 0; k < 8; ++k) {
            float4 u0 = E4[k * 8 + q * 2], u1 = E4[k * 8 + q * 2 + 1];
            a[m][k] = pack8(u0, u1);
            s += u0.x*u0.x + u0.y*u0.y + u0.z*u0.z + u0.w*u0.w
               + u1.x*u1.x + u1.y*u1.y + u1.z*u1.z + u1.w*u1.w;
        }
        s += __shfl_xor(s, 16, 64);
        s += __shfl_xor(s, 32, 64);
        e2m[m] = s;                  // e2 of row m*16 + l15 (replicated over q)
    }
    // redistribute: acc-row r of acc[m] is global row m*16 + q*4 + r
    float ainit[4][4]; int lb[4][4];
    #pragma unroll
    for (int m = 0; m < 4; ++m)
        #pragma unroll
        for (int r = 0; r < 4; ++r) {
            ainit[m][r] = -0.5f * __shfl(e2m[m], q * 4 + r, 64);
            lb[m][r] = __shfl(lab_self, m * 16 + q * 4 + r, 64);
        }

    float fsum = 0.0f;

    for (int ch = 0; ch < nchunk; ++ch) {
        asm volatile("s_waitcnt vmcnt(0)" ::: "memory");
        __builtin_amdgcn_s_barrier();

        const char* Bcur = smem + (ch & 1) * CHUNK_BYTES;
        if (ch + 1 < nchunk) {
            const char* src = Cimg + (size_t)(ch + 1) * CHUNK_BYTES;
            char* dst = smem + ((ch + 1) & 1) * CHUNK_BYTES;
            #pragma unroll
            for (int i = 0; i < 8; ++i)
                async_cp16(src + (size_t)(i * 256 + tid) * 16, dst + (i * 256 + tid) * 16);
        }

        const int colg = ch * 64 + wid * 16 + l15;
        const float c2v = -0.5f * c2l[colg];
        f32x4 acc[4];
        #pragma unroll
        for (int m = 0; m < 4; ++m)
            #pragma unroll
            for (int r = 0; r < 4; ++r)
                acc[m][r] = ainit[m][r] + c2v;   // => d2 = -2*acc after MFMA

        const char* Bw = Bcur + wid * 8192 + lane * 16;
        #pragma unroll
        for (int k = 0; k < 8; ++k) {
            bf16x8 b = *(const bf16x8*)(Bw + k * 1024);
            #pragma unroll
            for (int m = 0; m < 4; ++m)
                acc[m] = __builtin_amdgcn_mfma_f32_16x16x32_bf16(a[m][k], b, acc[m], 0, 0, 0);
        }

        // pos: select the label column (bf16-dot accuracy, averages out)
        #pragma unroll
        for (int m = 0; m < 4; ++m)
            #pragma unroll
            for (int r = 0; r < 4; ++r)
                fsum += (colg == lb[m][r]) ? fmaxf(-2.0f * acc[m][r], 0.0f) : 0.0f;

        // margin screen: any d2 < 2 (slack over margin^2=1 covers bf16 error)
        float mx = acc[0][0];
        #pragma unroll
        for (int m = 0; m < 4; ++m)
            #pragma unroll
            for (int r = 0; r < 4; ++r) mx = fmaxf(mx, acc[m][r]);
        if (__builtin_expect(__any(mx > -1.0f), 0)) {  // rare
            #pragma unroll
            for (int m = 0; m < 4; ++m)
                #pragma unroll
                for (int r = 0; r < 4; ++r) {
                    float d2 = fmaxf(-2.0f * acc[m][r], 0.0f);
                    if (d2 < 1.0f && colg != lb[m][r]) {
                        float t = 1.0f - sqrtf(d2);
                        fsum += t * t;
                    }
                }
        }
    }

    #pragma unroll
    for (int d = 32; d >= 1; d >>= 1) fsum += __shfl_xor(fsum, d, 64);
    __syncthreads();
    if (lane == 0) red[wid] = fsum;
    __syncthreads();
    if (tid == 0)
        atomicAdd(out, (red[0] + red[1] + red[2] + red[3]) * invB);
}

// ======================= fallback (round-1, verified) ========================
#define FB_THREADS 512
#define FB_SMEM 132672
__device__ int g_lab_is64;

__global__ void fb_detect_kernel(const unsigned* __restrict__ w, int nelem,
                                 float* __restrict__ out, int out_size) {
    __shared__ unsigned red[256];
    unsigned acc = 0;
    for (int i = threadIdx.x; i < nelem / 2; i += 256) acc |= w[2 * i + 1];
    red[threadIdx.x] = acc;
    __syncthreads();
    for (int s = 128; s > 0; s >>= 1) {
        if (threadIdx.x < s) red[threadIdx.x] |= red[threadIdx.x + s];
        __syncthreads();
    }
    if (threadIdx.x == 0) g_lab_is64 = (red[0] == 0u) ? 1 : 0;
    for (int i = threadIdx.x; i < out_size; i += 256) out[i] = 0.0f;
}

__global__ __launch_bounds__(FB_THREADS) void fb_loss_kernel(
    const float* __restrict__ emb, const float* __restrict__ cent,
    const int* __restrict__ labw, float* __restrict__ out,
    int nchunk, float invB) {
    extern __shared__ char smem[];
    char* Abf = smem;
    char* Cbf = smem + 65536;
    float* e2 = (float*)(smem + 131072);
    float* c2 = (float*)(smem + 131584);
    int* lab = (int*)(smem + 132096);
    float* red = (float*)(smem + 132608);

    const int tid = threadIdx.x, lane = tid & 63, wid = tid >> 6;
    const int row0 = blockIdx.x * 128;
    const int is64 = g_lab_is64;

    for (int j = 0; j < 16; ++j) {
        int f4 = tid + j * FB_THREADS;
        int r = f4 >> 6, c4 = f4 & 63;
        float4 v = ((const float4*)emb)[(size_t)(row0 + r) * 64 + c4];
        ushort4 h;
        h.x = f2bf(v.x); h.y = f2bf(v.y); h.z = f2bf(v.z); h.w = f2bf(v.w);
        int off = (c4 * 8) ^ ((r & 7) << 4);
        *(ushort4*)(Abf + r * 512 + off) = h;
        float s = v.x*v.x + v.y*v.y + v.z*v.z + v.w*v.w;
        #pragma unroll
        for (int m = 32; m >= 1; m >>= 1) s += __shfl_xor(s, m, 64);
        if (lane == 0) e2[r] = s;
    }
    if (tid < 128) {
        int b = row0 + tid;
        lab[tid] = is64 ? labw[2 * b] : labw[b];
    }
    __syncthreads();

    const int wr = wid >> 1, wc = wid & 1;
    const int l15 = lane & 15, l16 = lane >> 4;
    const int swz = (l15 & 7) << 4;

    float e2v[2][4]; int labv[2][4];
    #pragma unroll
    for (int m = 0; m < 2; ++m)
        #pragma unroll
        for (int r = 0; r < 4; ++r) {
            int rr = wr * 32 + m * 16 + l16 * 4 + r;
            e2v[m][r] = e2[rr]; labv[m][r] = lab[rr];
        }

    float fsum = 0.0f;
    for (int ch = 0; ch < nchunk; ++ch) {
        const float* cbase = cent + (size_t)ch * 128 * 256;
        for (int j = 0; j < 16; ++j) {
            int f4 = tid + j * FB_THREADS;
            int r = f4 >> 6, c4 = f4 & 63;
            float4 v = ((const float4*)cbase)[(size_t)r * 64 + c4];
            ushort4 h;
            h.x = f2bf(v.x); h.y = f2bf(v.y); h.z = f2bf(v.z); h.w = f2bf(v.w);
            int off = (c4 * 8) ^ ((r & 7) << 4);
            *(ushort4*)(Cbf + r * 512 + off) = h;
            float s = v.x*v.x + v.y*v.y + v.z*v.z + v.w*v.w;
            #pragma unroll
            for (int m = 32; m >= 1; m >>= 1) s += __shfl_xor(s, m, 64);
            if (lane == 0) c2[r] = s;
        }
        __syncthreads();

        f32x4 acc[2][4];
        #pragma unroll
        for (int m = 0; m < 2; ++m)
            #pragma unroll
            for (int n = 0; n < 4; ++n) acc[m][n] = (f32x4){0, 0, 0, 0};

        #pragma unroll
        for (int kk = 0; kk < 8; ++kk) {
            int kb = kk * 64 + l16 * 16;
            bf16x8 a[2], b[4];
            #pragma unroll
            for (int m = 0; m < 2; ++m)
                a[m] = *(const bf16x8*)(Abf + (wr * 32 + m * 16 + l15) * 512 + (kb ^ swz));
            #pragma unroll
            for (int n = 0; n < 4; ++n)
                b[n] = *(const bf16x8*)(Cbf + (wc * 64 + n * 16 + l15) * 512 + (kb ^ swz));
            #pragma unroll
            for (int m = 0; m < 2; ++m)
                #pragma unroll
                for (int n = 0; n < 4; ++n)
                    acc[m][n] = __builtin_amdgcn_mfma_f32_16x16x32_bf16(a[m], b[n], acc[m][n], 0, 0, 0);
        }

        float c2v[4]; int colg[4];
        #pragma unroll
        for (int n = 0; n < 4; ++n) {
            int cl = wc * 64 + n * 16 + l15;
            c2v[n] = c2[cl]; colg[n] = ch * 128 + cl;
        }
        unsigned need = 0;
        #pragma unroll
        for (int m = 0; m < 2; ++m)
            #pragma unroll
            for (int n = 0; n < 4; ++n)
                #pragma unroll
                for (int r = 0; r < 4; ++r) {
                    float d2 = fmaf(-2.0f, acc[m][n][r], e2v[m][r] + c2v[n]);
                    d2 = fmaxf(d2, 0.0f);
                    bool isp = (colg[n] == labv[m][r]);
                    fsum += isp ? d2 : 0.0f;
                    need |= (unsigned)((!isp) & (d2 < 1.0f)) << (m * 16 + n * 4 + r);
                }
        if (__any(need != 0)) {
            #pragma unroll
            for (int m = 0; m < 2; ++m)
                #pragma unroll
                for (int n = 0; n < 4; ++n)
                    #pragma unroll
                    for (int r = 0; r < 4; ++r)
                        if ((need >> (m * 16 + n * 4 + r)) & 1u) {
                            float d2 = fmaf(-2.0f, acc[m][n][r], e2v[m][r] + c2v[n]);
                            d2 = fmaxf(d2, 0.0f);
                            float t = 1.0f - sqrtf(d2);
                            fsum += t * t;
                        }
        }
        __syncthreads();
    }
    #pragma unroll
    for (int m = 32; m >= 1; m >>= 1) fsum += __shfl_xor(fsum, m, 64);
    if (lane == 0) red[wid] = fsum;
    __syncthreads();
    if (tid == 0) {
        float t = 0.0f;
        #pragma unroll
        for (int w = 0; w < 8; ++w) t += red[w];
        atomicAdd(out, t * invB);
    }
}

// =============================================================================
extern "C" void kernel_launch(void* const* d_in, const int* in_sizes, int n_in,
                              void* d_out, int out_size, void* d_ws, size_t ws_size,
                              hipStream_t stream) {
    const float* emb = (const float*)d_in[0];
    const float* cent = (const float*)d_in[1];
    const int* labw = (const int*)d_in[2];
    float* out = (float*)d_out;

    const int B = in_sizes[0] / 256;
    const int K = in_sizes[1] / 256;
    const float invB = 1.0f / (float)B;

    char* ws = (char*)d_ws;
    const size_t off_c2 = 0;                     // K floats
    const size_t off_cimg = (size_t)K * 4 + 4096;
    const size_t req = off_cimg + (size_t)K * 512;

    if (ws_size >= req) {
        const int ncb = K / 16;                  // 64 col-blocks of 16
        const int nblk = (ncb + 3) / 4;          // 16 image blocks
        cent_prep_kernel<<<nblk + 1, 256, 0, stream>>>(
            cent, ws + off_cimg, (float*)(ws + off_c2), out, out_size, ncb, nblk);

        hipFuncSetAttribute(reinterpret_cast<const void*>(main7_kernel),
                            hipFuncAttributeMaxDynamicSharedMemorySize, MAIN_SMEM);
        main7_kernel<<<B / 64, 256, MAIN_SMEM, stream>>>(
            emb, ws + off_cimg, (const float*)(ws + off_c2), labw, in_sizes[2],
            out, K, K / 64, invB);
    } else {
        fb_detect_kernel<<<1, 256, 0, stream>>>((const unsigned*)d_in[2], in_sizes[2],
                                                out, out_size);
        hipFuncSetAttribute(reinterpret_cast<const void*>(fb_loss_kernel),
                            hipFuncAttributeMaxDynamicSharedMemorySize, FB_SMEM);
        fb_loss_kernel<<<B / 128, FB_THREADS, FB_SMEM, stream>>>(
            emb, cent, labw, out, K / 128, invB);
    }
}

// Round 12
// 45.810 us; speedup vs baseline: 1.4384x; 1.4384x over previous
//
#include <hip/hip_runtime.h>
#include <hip/hip_bf16.h>
#include <math.h>

typedef short bf16x8 __attribute__((ext_vector_type(8)));
typedef float f32x4  __attribute__((ext_vector_type(4)));

static __device__ __forceinline__ unsigned short f2bf(float x) {
    unsigned u = __builtin_bit_cast(unsigned, x);
    return (unsigned short)((u + 0x7fffu + ((u >> 16) & 1u)) >> 16);
}

static __device__ __forceinline__ bf16x8 pack8(float4 u0, float4 u1) {
    bf16x8 f;
    f[0] = (short)f2bf(u0.x); f[1] = (short)f2bf(u0.y);
    f[2] = (short)f2bf(u0.z); f[3] = (short)f2bf(u0.w);
    f[4] = (short)f2bf(u1.x); f[5] = (short)f2bf(u1.y);
    f[6] = (short)f2bf(u1.z); f[7] = (short)f2bf(u1.w);
    return f;
}

static __device__ __forceinline__ void async_cp16(const void* gsrc, void* ldsdst) {
    __builtin_amdgcn_global_load_lds(
        (const __attribute__((address_space(1))) void*)gsrc,
        (__attribute__((address_space(3))) void*)ldsdst, 16, 0, 0);
}

template<int IMM> static __device__ __forceinline__ void wait_vm() {
    if constexpr (IMM == 16)     asm volatile("s_waitcnt vmcnt(16)" ::: "memory");
    else if constexpr (IMM == 8) asm volatile("s_waitcnt vmcnt(8)"  ::: "memory");
    else                         asm volatile("s_waitcnt vmcnt(0)"  ::: "memory");
}

// ---- cent_prep (wide): 256 thr; blocks [0,nblk): image+c2; block nblk: zero --
// img[cb16][k][lane][j] = cent[cb16*16 + (lane&15)][k*32 + (lane>>4)*8 + j]
__global__ __launch_bounds__(256) void cent_prep_kernel(
    const float* __restrict__ cent, char* __restrict__ Cimg,
    float* __restrict__ c2g, float* __restrict__ out, int out_size,
    int ncb, int nblk) {
    const int tid = threadIdx.x, lane = tid & 63, wv = tid >> 6;
    if ((int)blockIdx.x < nblk) {
        const int cb = blockIdx.x * 4 + wv;
        if (cb < ncb) {
            const int r = cb * 16 + (lane & 15);
            const int q = lane >> 4;
            const float4* C4 = (const float4*)cent;
            float s = 0.0f;
            #pragma unroll
            for (int k = 0; k < 8; ++k) {
                int fidx = r * 64 + k * 8 + q * 2;
                float4 u0 = C4[fidx], u1 = C4[fidx + 1];
                *(bf16x8*)(Cimg + ((size_t)(cb * 8 + k) * 64 + lane) * 16) = pack8(u0, u1);
                s += u0.x*u0.x + u0.y*u0.y + u0.z*u0.z + u0.w*u0.w
                   + u1.x*u1.x + u1.y*u1.y + u1.z*u1.z + u1.w*u1.w;
            }
            s += __shfl_xor(s, 16, 64);
            s += __shfl_xor(s, 32, 64);
            if (lane < 16) c2g[cb * 16 + lane] = s;
        }
    } else {
        for (int i = tid; i < out_size; i += 256) out[i] = 0.0f;
    }
}

// ---- main8: 256 blocks (1/CU) x 256 thr; wave = 64 rows x 32 cols. ----------
// a[4][8] inline-converted; acc[4][2]; d2 = -2*acc via e2/c2 folding; pos from
// the MFMA dot (validated R10/R11, absmax 0.0). Depth-2 counted-vmcnt pipeline:
// 4 x 32KB LDS buffers, fills for t+2 issued at top of t, steady wait
// vmcnt(16) (fills(t) oldest => guaranteed landed), peeled tail vmcnt(8)/(0).
// Raw s_barrier in-loop (ds_reads consumed by MFMA pre-barrier; fill->read
// ordering via counted vmcnt). (256,1): only config that avoids the 128-VGPR
// cap + spill (R4/R5/R7/R10 evidence).
#define CHUNK_BYTES 32768
// LDS: buf[4] @0 (128KB), c2l @131072 (4KB), det @135168 (16B), red @135184
#define MAIN_SMEM 135232

__global__ __launch_bounds__(256, 1) void main8_kernel(
    const float* __restrict__ emb, const char* __restrict__ Cimg,
    const float* __restrict__ c2g, const int* __restrict__ labw, int lab_nelem,
    float* __restrict__ out, int K, int nchunk, float invB) {
    extern __shared__ char smem[];
    float*    c2l = (float*)(smem + 131072);
    unsigned* det = (unsigned*)(smem + 135168);
    float*    red = (float*)(smem + 135184);

    const int tid = threadIdx.x, lane = tid & 63, wid = tid >> 6;
    const int wr = wid >> 1;          // row half: 64 rows
    const int wc = wid & 1;           // col half: 32 of the 64 chunk cols
    const int brow0 = blockIdx.x * 128;
    const int l15 = lane & 15, q = lane >> 4;

#define ISSUE_FILLS(t_) do {                                                  \
        const char* s_ = Cimg + (size_t)(t_) * CHUNK_BYTES;                   \
        char* d_ = smem + (size_t)((t_) & 3) * CHUNK_BYTES;                   \
        _Pragma("unroll")                                                     \
        for (int i_ = 0; i_ < 8; ++i_)                                        \
            async_cp16(s_ + (i_ * 256 + tid) * 16, d_ + (i_ * 256 + tid) * 16); \
    } while (0)

    // fills for chunks 0 and 1 FIRST (they must be the oldest vmem ops)
    ISSUE_FILLS(0);
    ISSUE_FILLS(1);
    asm volatile("" ::: "memory");   // pin fill issue order

    // c2 -> LDS
    for (int i = tid; i < K; i += 256) c2l[i] = c2g[i];

    // label-width detect from a fixed window (identical in all blocks)
    {
        int npairs = lab_nelem / 2; if (npairs > 4096) npairs = 4096;
        unsigned accw = 0;
        const unsigned* w = (const unsigned*)labw;
        for (int i = tid; i < npairs; i += 256) accw |= w[2 * i + 1];
        #pragma unroll
        for (int d = 32; d >= 1; d >>= 1) accw |= __shfl_xor(accw, d, 64);
        if (lane == 0) det[wid] = accw;
    }
    __syncthreads();
    const int is32 = ((det[0] | det[1] | det[2] | det[3]) != 0);
    // label of this wave's row (wr*64 + lane)
    const int lab_self = is32 ? labw[brow0 + wr * 64 + lane]
                              : labw[2 * (brow0 + wr * 64 + lane)];

    // A: this wave's 64 rows -> bf16 fragments; e2 per row via shfl
    bf16x8 a[4][8];
    float e2m[4];
    #pragma unroll
    for (int m = 0; m < 4; ++m) {
        const int rg = brow0 + wr * 64 + m * 16 + l15;
        const float4* E4 = (const float4*)emb + (size_t)rg * 64;
        float s = 0.0f;
        #pragma unroll
        for (int k = 0; k < 8; ++k) {
            float4 u0 = E4[k * 8 + q * 2], u1 = E4[k * 8 + q * 2 + 1];
            a[m][k] = pack8(u0, u1);
            s += u0.x*u0.x + u0.y*u0.y + u0.z*u0.z + u0.w*u0.w
               + u1.x*u1.x + u1.y*u1.y + u1.z*u1.z + u1.w*u1.w;
        }
        s += __shfl_xor(s, 16, 64);
        s += __shfl_xor(s, 32, 64);
        e2m[m] = s;                    // e2 of row wr*64 + m*16 + l15
    }
    // acc-row r of tile m is global row wr*64 + m*16 + q*4 + r
    float ainit[4][4]; int lb[4][4];
    #pragma unroll
    for (int m = 0; m < 4; ++m)
        #pragma unroll
        for (int r = 0; r < 4; ++r) {
            ainit[m][r] = -0.5f * __shfl(e2m[m], q * 4 + r, 64);
            lb[m][r] = __shfl(lab_self, m * 16 + q * 4 + r, 64);
        }

    float fsum = 0.0f;
    __syncthreads();   // c2l/det visible (also drains prologue vmem)

#define CHUNK_BODY(t_)  do {                                                  \
        const char* Bbuf = smem + (size_t)((t_) & 3) * CHUNK_BYTES;           \
        const int cg0 = (t_) * 64 + wc * 32 + l15;                            \
        const float c2v0 = -0.5f * c2l[cg0];                                  \
        const float c2v1 = -0.5f * c2l[cg0 + 16];                             \
        f32x4 acc[4][2];                                                      \
        _Pragma("unroll")                                                     \
        for (int m = 0; m < 4; ++m)                                           \
            _Pragma("unroll")                                                 \
            for (int r = 0; r < 4; ++r) {                                     \
                acc[m][0][r] = ainit[m][r] + c2v0;                            \
                acc[m][1][r] = ainit[m][r] + c2v1;                            \
            }                                                                 \
        const char* Bw = Bbuf + wc * 16384 + lane * 16;                       \
        _Pragma("unroll")                                                     \
        for (int k = 0; k < 8; ++k) {                                         \
            bf16x8 b0 = *(const bf16x8*)(Bw + k * 1024);                      \
            bf16x8 b1 = *(const bf16x8*)(Bw + 8192 + k * 1024);               \
            _Pragma("unroll")                                                 \
            for (int m = 0; m < 4; ++m) {                                     \
                acc[m][0] = __builtin_amdgcn_mfma_f32_16x16x32_bf16(a[m][k], b0, acc[m][0], 0, 0, 0); \
                acc[m][1] = __builtin_amdgcn_mfma_f32_16x16x32_bf16(a[m][k], b1, acc[m][1], 0, 0, 0); \
            }                                                                 \
        }                                                                     \
        float mx = acc[0][0][0];                                              \
        _Pragma("unroll")                                                     \
        for (int m = 0; m < 4; ++m)                                           \
            _Pragma("unroll")                                                 \
            for (int r = 0; r < 4; ++r) {                                     \
                fsum += (cg0 == lb[m][r]) ? fmaxf(-2.0f * acc[m][0][r], 0.0f) : 0.0f;      \
                fsum += (cg0 + 16 == lb[m][r]) ? fmaxf(-2.0f * acc[m][1][r], 0.0f) : 0.0f; \
                mx = fmaxf(mx, fmaxf(acc[m][0][r], acc[m][1][r]));            \
            }                                                                 \
        if (__builtin_expect(__any(mx > -1.0f), 0)) {                         \
            _Pragma("unroll")                                                 \
            for (int m = 0; m < 4; ++m)                                       \
                _Pragma("unroll")                                             \
                for (int n = 0; n < 2; ++n)                                   \
                    _Pragma("unroll")                                         \
                    for (int r = 0; r < 4; ++r) {                             \
                        float d2 = fmaxf(-2.0f * acc[m][n][r], 0.0f);         \
                        int cg = cg0 + n * 16;                                \
                        if (d2 < 1.0f && cg != lb[m][r]) {                    \
                            float tt = 1.0f - sqrtf(d2);                      \
                            fsum += tt * tt;                                  \
                        }                                                     \
                    }                                                         \
        }                                                                     \
    } while (0)

    // steady loop: fills(t+2) in flight, wait only for fills(t)
    int t = 0;
    for (; t < nchunk - 2; ++t) {
        __builtin_amdgcn_s_barrier();
        ISSUE_FILLS(t + 2);
        wait_vm<16>();
        CHUNK_BODY(t);
    }
    // peeled tail
    __builtin_amdgcn_s_barrier();
    wait_vm<8>();
    CHUNK_BODY(t);
    ++t;
    __builtin_amdgcn_s_barrier();
    wait_vm<0>();
    CHUNK_BODY(t);

#undef CHUNK_BODY
#undef ISSUE_FILLS

    #pragma unroll
    for (int d = 32; d >= 1; d >>= 1) fsum += __shfl_xor(fsum, d, 64);
    __syncthreads();
    if (lane == 0) red[wid] = fsum;
    __syncthreads();
    if (tid == 0)
        atomicAdd(out, (red[0] + red[1] + red[2] + red[3]) * invB);
}

// ======================= fallback (round-1, verified) ========================
#define FB_THREADS 512
#define FB_SMEM 132672
__device__ int g_lab_is64;

__global__ void fb_detect_kernel(const unsigned* __restrict__ w, int nelem,
                                 float* __restrict__ out, int out_size) {
    __shared__ unsigned red[256];
    unsigned acc = 0;
    for (int i = threadIdx.x; i < nelem / 2; i += 256) acc |= w[2 * i + 1];
    red[threadIdx.x] = acc;
    __syncthreads();
    for (int s = 128; s > 0; s >>= 1) {
        if (threadIdx.x < s) red[threadIdx.x] |= red[threadIdx.x + s];
        __syncthreads();
    }
    if (threadIdx.x == 0) g_lab_is64 = (red[0] == 0u) ? 1 : 0;
    for (int i = threadIdx.x; i < out_size; i += 256) out[i] = 0.0f;
}

__global__ __launch_bounds__(FB_THREADS) void fb_loss_kernel(
    const float* __restrict__ emb, const float* __restrict__ cent,
    const int* __restrict__ labw, float* __restrict__ out,
    int nchunk, float invB) {
    extern __shared__ char smem[];
    char* Abf = smem;
    char* Cbf = smem + 65536;
    float* e2 = (float*)(smem + 131072);
    float* c2 = (float*)(smem + 131584);
    int* lab = (int*)(smem + 132096);
    float* red = (float*)(smem + 132608);

    const int tid = threadIdx.x, lane = tid & 63, wid = tid >> 6;
    const int row0 = blockIdx.x * 128;
    const int is64 = g_lab_is64;

    for (int j = 0; j < 16; ++j) {
        int f4 = tid + j * FB_THREADS;
        int r = f4 >> 6, c4 = f4 & 63;
        float4 v = ((const float4*)emb)[(size_t)(row0 + r) * 64 + c4];
        ushort4 h;
        h.x = f2bf(v.x); h.y = f2bf(v.y); h.z = f2bf(v.z); h.w = f2bf(v.w);
        int off = (c4 * 8) ^ ((r & 7) << 4);
        *(ushort4*)(Abf + r * 512 + off) = h;
        float s = v.x*v.x + v.y*v.y + v.z*v.z + v.w*v.w;
        #pragma unroll
        for (int m = 32; m >= 1; m >>= 1) s += __shfl_xor(s, m, 64);
        if (lane == 0) e2[r] = s;
    }
    if (tid < 128) {
        int b = row0 + tid;
        lab[tid] = is64 ? labw[2 * b] : labw[b];
    }
    __syncthreads();

    const int wr = wid >> 1, wc = wid & 1;
    const int l15 = lane & 15, l16 = lane >> 4;
    const int swz = (l15 & 7) << 4;

    float e2v[2][4]; int labv[2][4];
    #pragma unroll
    for (int m = 0; m < 2; ++m)
        #pragma unroll
        for (int r = 0; r < 4; ++r) {
            int rr = wr * 32 + m * 16 + l16 * 4 + r;
            e2v[m][r] = e2[rr]; labv[m][r] = lab[rr];
        }

    float fsum = 0.0f;
    for (int ch = 0; ch < nchunk; ++ch) {
        const float* cbase = cent + (size_t)ch * 128 * 256;
        for (int j = 0; j < 16; ++j) {
            int f4 = tid + j * FB_THREADS;
            int r = f4 >> 6, c4 = f4 & 63;
            float4 v = ((const float4*)cbase)[(size_t)r * 64 + c4];
            ushort4 h;
            h.x = f2bf(v.x); h.y = f2bf(v.y); h.z = f2bf(v.z); h.w = f2bf(v.w);
            int off = (c4 * 8) ^ ((r & 7) << 4);
            *(ushort4*)(Cbf + r * 512 + off) = h;
            float s = v.x*v.x + v.y*v.y + v.z*v.z + v.w*v.w;
            #pragma unroll
            for (int m = 32; m >= 1; m >>= 1) s += __shfl_xor(s, m, 64);
            if (lane == 0) c2[r] = s;
        }
        __syncthreads();

        f32x4 acc[2][4];
        #pragma unroll
        for (int m = 0; m < 2; ++m)
            #pragma unroll
            for (int n = 0; n < 4; ++n) acc[m][n] = (f32x4){0, 0, 0, 0};

        #pragma unroll
        for (int kk = 0; kk < 8; ++kk) {
            int kb = kk * 64 + l16 * 16;
            bf16x8 a[2], b[4];
            #pragma unroll
            for (int m = 0; m < 2; ++m)
                a[m] = *(const bf16x8*)(Abf + (wr * 32 + m * 16 + l15) * 512 + (kb ^ swz));
            #pragma unroll
            for (int n = 0; n < 4; ++n)
                b[n] = *(const bf16x8*)(Cbf + (wc * 64 + n * 16 + l15) * 512 + (kb ^ swz));
            #pragma unroll
            for (int m = 0; m < 2; ++m)
                #pragma unroll
                for (int n = 0; n < 4; ++n)
                    acc[m][n] = __builtin_amdgcn_mfma_f32_16x16x32_bf16(a[m], b[n], acc[m][n], 0, 0, 0);
        }

        float c2v[4]; int colg[4];
        #pragma unroll
        for (int n = 0; n < 4; ++n) {
            int cl = wc * 64 + n * 16 + l15;
            c2v[n] = c2[cl]; colg[n] = ch * 128 + cl;
        }
        unsigned need = 0;
        #pragma unroll
        for (int m = 0; m < 2; ++m)
            #pragma unroll
            for (int n = 0; n < 4; ++n)
                #pragma unroll
                for (int r = 0; r < 4; ++r) {
                    float d2 = fmaf(-2.0f, acc[m][n][r], e2v[m][r] + c2v[n]);
                    d2 = fmaxf(d2, 0.0f);
                    bool isp = (colg[n] == labv[m][r]);
                    fsum += isp ? d2 : 0.0f;
                    need |= (unsigned)((!isp) & (d2 < 1.0f)) << (m * 16 + n * 4 + r);
                }
        if (__any(need != 0)) {
            #pragma unroll
            for (int m = 0; m < 2; ++m)
                #pragma unroll
                for (int n = 0; n < 4; ++n)
                    #pragma unroll
                    for (int r = 0; r < 4; ++r)
                        if ((need >> (m * 16 + n * 4 + r)) & 1u) {
                            float d2 = fmaf(-2.0f, acc[m][n][r], e2v[m][r] + c2v[n]);
                            d2 = fmaxf(d2, 0.0f);
                            float t = 1.0f - sqrtf(d2);
                            fsum += t * t;
                        }
        }
        __syncthreads();
    }
    #pragma unroll
    for (int m = 32; m >= 1; m >>= 1) fsum += __shfl_xor(fsum, m, 64);
    if (lane == 0) red[wid] = fsum;
    __syncthreads();
    if (tid == 0) {
        float t = 0.0f;
        #pragma unroll
        for (int w = 0; w < 8; ++w) t += red[w];
        atomicAdd(out, t * invB);
    }
}

// =============================================================================
extern "C" void kernel_launch(void* const* d_in, const int* in_sizes, int n_in,
                              void* d_out, int out_size, void* d_ws, size_t ws_size,
                              hipStream_t stream) {
    const float* emb = (const float*)d_in[0];
    const float* cent = (const float*)d_in[1];
    const int* labw = (const int*)d_in[2];
    float* out = (float*)d_out;

    const int B = in_sizes[0] / 256;
    const int K = in_sizes[1] / 256;
    const float invB = 1.0f / (float)B;

    char* ws = (char*)d_ws;
    const size_t off_c2 = 0;                     // K floats
    const size_t off_cimg = (size_t)K * 4 + 4096;
    const size_t req = off_cimg + (size_t)K * 512;

    if (ws_size >= req && K >= 256) {
        const int ncb = K / 16;                  // 64 col-blocks of 16
        const int nblk = (ncb + 3) / 4;          // 16 image blocks
        cent_prep_kernel<<<nblk + 1, 256, 0, stream>>>(
            cent, ws + off_cimg, (float*)(ws + off_c2), out, out_size, ncb, nblk);

        hipFuncSetAttribute(reinterpret_cast<const void*>(main8_kernel),
                            hipFuncAttributeMaxDynamicSharedMemorySize, MAIN_SMEM);
        main8_kernel<<<B / 128, 256, MAIN_SMEM, stream>>>(
            emb, ws + off_cimg, (const float*)(ws + off_c2), labw, in_sizes[2],
            out, K, K / 64, invB);
    } else {
        fb_detect_kernel<<<1, 256, 0, stream>>>((const unsigned*)d_in[2], in_sizes[2],
                                                out, out_size);
        hipFuncSetAttribute(reinterpret_cast<const void*>(fb_loss_kernel),
                            hipFuncAttributeMaxDynamicSharedMemorySize, FB_SMEM);
        fb_loss_kernel<<<B / 128, FB_THREADS, FB_SMEM, stream>>>(
            emb, cent, labw, out, K / 128, invB);
    }
}